// Round 2
// baseline (13794.641 us; speedup 1.0000x reference)
//
#include <hip/hip_runtime.h>
#include <cstdint>
#include <cstddef>

// Problem constants (match reference)
#define Bn 16384
#define Dn 768
#define Hn 768
#define G4 3072      // 4*H
#define En 4
#define Tn 10

__device__ __forceinline__ float sigm(float x) { return 1.f / (1.f + expf(-x)); }

// ---------------------------------------------------------------------------
// Tiled fp32 GEMM:  C[M,N] = A[M,K] @ Bt[N,K]^T  (+ src) (+ bias) (relu?)
// 128x128 tile, BK=16, 256 threads, 8x8 per-thread microtile.
// blockIdx.z group offsets (elements) for grouped per-expert GEMM.
// M,N,K multiples of tile sizes here.
// ---------------------------------------------------------------------------
template <bool ADD, bool BIAS, bool RELU>
__global__ __launch_bounds__(256) void gemm128(
    const float* __restrict__ A, int lda,
    const float* __restrict__ Bt, int ldb,
    float* __restrict__ C, int ldc,
    const float* __restrict__ src, int ldsrc,
    const float* __restrict__ bias,
    int M, int N, int K,
    long aZ, long bZ, long cZ, long biasZ)
{
    if (blockIdx.z) {
        A  += (long)blockIdx.z * aZ;
        Bt += (long)blockIdx.z * bZ;
        C  += (long)blockIdx.z * cZ;
        if (BIAS) bias += (long)blockIdx.z * biasZ;
    }
    __shared__ float As[16][132];   // [k][m], +4 pad
    __shared__ float Bs[16][132];   // [k][n]

    const int tid = threadIdx.x;
    const int m0 = blockIdx.x * 128;
    const int n0 = blockIdx.y * 128;
    const int tx = tid & 15, ty = tid >> 4;

    float acc[8][8];
#pragma unroll
    for (int i = 0; i < 8; i++)
#pragma unroll
        for (int j = 0; j < 8; j++) acc[i][j] = 0.f;

    for (int k0 = 0; k0 < K; k0 += 16) {
        __syncthreads();   // protect LDS from previous iteration's readers
#pragma unroll
        for (int u = 0; u < 2; u++) {
            int idx = tid + u * 256;       // 0..511 -> 128 rows x 4 float4
            int row = idx >> 2;
            int c4  = (idx & 3) << 2;
            float4 av = *(const float4*)(A + (long)(m0 + row) * lda + k0 + c4);
            As[c4 + 0][row] = av.x; As[c4 + 1][row] = av.y;
            As[c4 + 2][row] = av.z; As[c4 + 3][row] = av.w;
            float4 bv = *(const float4*)(Bt + (long)(n0 + row) * ldb + k0 + c4);
            Bs[c4 + 0][row] = bv.x; Bs[c4 + 1][row] = bv.y;
            Bs[c4 + 2][row] = bv.z; Bs[c4 + 3][row] = bv.w;
        }
        __syncthreads();
#pragma unroll
        for (int kk = 0; kk < 16; kk++) {
            float a[8], b[8];
            *(float4*)&a[0] = *(const float4*)&As[kk][ty * 8];
            *(float4*)&a[4] = *(const float4*)&As[kk][ty * 8 + 4];
            *(float4*)&b[0] = *(const float4*)&Bs[kk][tx * 8];
            *(float4*)&b[4] = *(const float4*)&Bs[kk][tx * 8 + 4];
#pragma unroll
            for (int i = 0; i < 8; i++)
#pragma unroll
                for (int j = 0; j < 8; j++)
                    acc[i][j] = fmaf(a[i], b[j], acc[i][j]);
        }
    }

    const int rb = m0 + ty * 8, cb = n0 + tx * 8;
#pragma unroll
    for (int i = 0; i < 8; i++) {
        long co = (long)(rb + i) * ldc + cb;
#pragma unroll
        for (int j = 0; j < 8; j++) {
            float v = acc[i][j];
            if (BIAS) v += bias[cb + j];
            if (ADD)  v += src[(long)(rb + i) * ldsrc + cb + j];
            if (RELU) v = v > 0.f ? v : 0.f;
            C[co + j] = v;
        }
    }
}

// bsum = bi + bh
__global__ void bias_sum_k(const float* __restrict__ bi, const float* __restrict__ bh,
                           float* __restrict__ bsum) {
    int i = blockIdx.x * 256 + threadIdx.x;
    if (i < G4) bsum[i] = bi[i] + bh[i];
}

// One block per batch row: LSTM cell pointwise + halting head.
__global__ __launch_bounds__(256) void lstm_step_k(
    const float* __restrict__ gates, float* __restrict__ c, float* __restrict__ h,
    float* __restrict__ hsum, float* __restrict__ hp, float* __restrict__ rem,
    const float* __restrict__ Whalt, const float* __restrict__ bhalt)
{
    const int row = blockIdx.x, tid = threadIdx.x;
    const float* g = gates + (size_t)row * G4;
    const size_t hb = (size_t)row * Hn;
    float part = 0.f;
#pragma unroll
    for (int u = 0; u < 3; u++) {
        int j = tid + u * 256;
        float ig = g[j], fg = g[Hn + j], gg = g[2 * Hn + j], og = g[3 * Hn + j];
        float cv = c[hb + j];
        cv = sigm(fg) * cv + sigm(ig) * tanhf(gg);
        float hv = sigm(og) * tanhf(cv);
        c[hb + j] = cv;
        h[hb + j] = hv;
        hsum[hb + j] += hv;
        part += hv * Whalt[j];
    }
    __shared__ float red[256];
    red[tid] = part;
    __syncthreads();
    for (int s = 128; s > 0; s >>= 1) {
        if (tid < s) red[tid] += red[tid + s];
        __syncthreads();
    }
    if (tid == 0) {
        float y = sigm(red[0] + bhalt[0]);
        float hpv = hp[row];
        float nhp = hpv + y * (1.f - hpv);
        hp[row] = nhp;
        rem[row] += 1.f - nhp;   // reference: rem += 1 - hp_new
    }
}

// xm = rem[row] * hsum / T
__global__ void avg_k(const float* __restrict__ hsum, const float* __restrict__ rem,
                      float* __restrict__ xm) {
    int i = blockIdx.x * 256 + threadIdx.x;
    int row = i / Hn;
    xm[i] = rem[row] * hsum[i] * (1.f / (float)Tn);
}

// One block per row: 4 gate logits, top-2, softmax weights.
__global__ __launch_bounds__(256) void moe_gate_k(
    const float* __restrict__ xm, const float* __restrict__ gW,
    const float* __restrict__ gb, float* __restrict__ wout, int* __restrict__ idxout)
{
    const int row = blockIdx.x, tid = threadIdx.x;
    const float* xr = xm + (size_t)row * Hn;
    float p[4] = {0.f, 0.f, 0.f, 0.f};
#pragma unroll
    for (int u = 0; u < 3; u++) {
        int j = tid + u * 256;
        float xv = xr[j];
        p[0] += xv * gW[j];
        p[1] += xv * gW[Hn + j];
        p[2] += xv * gW[2 * Hn + j];
        p[3] += xv * gW[3 * Hn + j];
    }
    __shared__ float red[256];
    __shared__ float logit[4];
    for (int e = 0; e < 4; e++) {
        red[tid] = p[e];
        __syncthreads();
        for (int s = 128; s > 0; s >>= 1) {
            if (tid < s) red[tid] += red[tid + s];
            __syncthreads();
        }
        if (tid == 0) logit[e] = red[0] + gb[e];
        __syncthreads();
    }
    if (tid == 0) {
        int i0 = 0;
        for (int e = 1; e < 4; e++) if (logit[e] > logit[i0]) i0 = e;
        int i1 = -1;
        for (int e = 0; e < 4; e++) {
            if (e == i0) continue;
            if (i1 < 0 || logit[e] > logit[i1]) i1 = e;
        }
        float l0 = logit[i0], l1 = logit[i1];
        float ex = expf(l1 - l0);           // <= 1
        float w0 = 1.f / (1.f + ex);
        float w1 = ex / (1.f + ex);
        wout[2 * row] = w0; wout[2 * row + 1] = w1;
        idxout[2 * row] = i0; idxout[2 * row + 1] = i1;
    }
}

// out[b,d] = w0*eo[b,i0,d] + w1*eo[b,i1,d]
__global__ void combine_k(const float* __restrict__ eo, const float* __restrict__ w,
                          const int* __restrict__ idx, float* __restrict__ out) {
    int i = blockIdx.x * 256 + threadIdx.x;
    int row = i / Hn;
    int d = i - row * Hn;
    size_t base = (size_t)row * G4;
    float v = w[2 * row]     * eo[base + (size_t)idx[2 * row]     * Hn + d]
            + w[2 * row + 1] * eo[base + (size_t)idx[2 * row + 1] * Hn + d];
    out[i] = v;
}

__global__ __launch_bounds__(256) void layernorm_k(
    const float* __restrict__ in, const float* __restrict__ gamma,
    const float* __restrict__ beta, float* __restrict__ out)
{
    const int row = blockIdx.x, tid = threadIdx.x;
    const float* xr = in + (size_t)row * Dn;
    float v[3], s = 0.f, s2 = 0.f;
#pragma unroll
    for (int u = 0; u < 3; u++) {
        v[u] = xr[tid + u * 256];
        s += v[u];
        s2 += v[u] * v[u];
    }
    __shared__ float r1[256], r2[256];
    __shared__ float smu, srs;
    r1[tid] = s; r2[tid] = s2;
    __syncthreads();
    for (int st = 128; st > 0; st >>= 1) {
        if (tid < st) { r1[tid] += r1[tid + st]; r2[tid] += r2[tid + st]; }
        __syncthreads();
    }
    if (tid == 0) {
        float mu = r1[0] * (1.f / (float)Dn);
        float var = r2[0] * (1.f / (float)Dn) - mu * mu;
        smu = mu;
        srs = 1.f / sqrtf(var + 1e-5f);
    }
    __syncthreads();
    float mu = smu, rs = srs;
#pragma unroll
    for (int u = 0; u < 3; u++) {
        int j = tid + u * 256;
        out[(size_t)row * Dn + j] = (v[u] - mu) * rs * gamma[j] + beta[j];
    }
}

extern "C" void kernel_launch(void* const* d_in, const int* in_sizes, int n_in,
                              void* d_out, int out_size, void* d_ws, size_t ws_size,
                              hipStream_t stream) {
    (void)in_sizes; (void)n_in; (void)out_size;
    const float* x     = (const float*)d_in[0];
    const float* Wi    = (const float*)d_in[1];
    const float* Wh    = (const float*)d_in[2];
    const float* bi    = (const float*)d_in[3];
    const float* bh    = (const float*)d_in[4];
    const float* Whalt = (const float*)d_in[5];
    const float* bhalt = (const float*)d_in[6];
    const float* gateW = (const float*)d_in[7];
    const float* gateb = (const float*)d_in[8];
    const float* W1    = (const float*)d_in[9];
    const float* b1    = (const float*)d_in[10];
    const float* W2    = (const float*)d_in[11];
    const float* b2    = (const float*)d_in[12];
    const float* gamma = (const float*)d_in[13];
    const float* beta  = (const float*)d_in[14];
    float* out = (float*)d_out;

    // -----------------------------------------------------------------------
    // Adaptive batch chunking: every batch row is independent end-to-end,
    // so pick the largest power-of-two row-chunk Bc whose workspace fits.
    // Per-row floats: xwi 3072 + gates 3072 + h/c/hsum 768*3 + hp/rem 2
    //                 + wbuf 2 + ibuf 2  = 8452; plus bsum 3072 + slack.
    // -----------------------------------------------------------------------
    int Bc = Bn;
    while (Bc > 128) {
        size_t need = ((size_t)Bc * 8452 + G4 + 256) * sizeof(float);
        if (need <= ws_size) break;
        Bc >>= 1;
    }
    const int nChunks = Bn / Bc;

    const size_t N1c = (size_t)Bc * G4;
    const size_t BHc = (size_t)Bc * Hn;
    float* f    = (float*)d_ws;
    float* xwi  = f;                 // N1c (reused as eo in MoE)
    float* gates= xwi + N1c;         // N1c (reused as hmid in MoE)
    float* h    = gates + N1c;       // BHc (reused as xm after LSTM)
    float* c    = h + BHc;           // BHc (reused as pre-LN buffer)
    float* hsum = c + BHc;           // BHc
    float* hp   = hsum + BHc;        // Bc
    float* rem  = hp + Bc;           // Bc
    float* wbuf = rem + Bc;          // 2*Bc
    int*   ibuf = (int*)(wbuf + 2 * Bc);     // 2*Bc ints
    float* bsum = (float*)(ibuf + 2 * Bc);   // G4

    bias_sum_k<<<(G4 + 255) / 256, 256, 0, stream>>>(bi, bh, bsum);

    dim3 gBig(Bc / 128, G4 / 128, 1);
    dim3 gGrp(Bc / 128, Hn / 128, En);
    dim3 blk(256);
    const int ew_grid = (int)(BHc / 256);

    for (int ch = 0; ch < nChunks; ch++) {
        const float* xc = x + (size_t)ch * Bc * Dn;
        float* outc = out + (size_t)ch * Bc * Dn;

        // Zero-init per-chunk state (ws is poisoned 0xAA before every call)
        hipMemsetAsync(c, 0, BHc * sizeof(float), stream);
        hipMemsetAsync(hsum, 0, BHc * sizeof(float), stream);
        hipMemsetAsync(hp, 0, Bc * sizeof(float), stream);
        hipMemsetAsync(rem, 0, Bc * sizeof(float), stream);

        // xWi = x @ Wi^T + (bi + bh)
        gemm128<false, true, false><<<gBig, blk, 0, stream>>>(
            xc, Dn, Wi, Dn, xwi, G4, nullptr, 0, bsum, Bc, G4, Dn, 0, 0, 0, 0);

        // t = 0: h == 0  ->  gates == xwi
        lstm_step_k<<<Bc, blk, 0, stream>>>(xwi, c, h, hsum, hp, rem, Whalt, bhalt);
        for (int t = 1; t < Tn; t++) {
            gemm128<true, false, false><<<gBig, blk, 0, stream>>>(
                h, Hn, Wh, Hn, gates, G4, xwi, G4, nullptr, Bc, G4, Hn, 0, 0, 0, 0);
            lstm_step_k<<<Bc, blk, 0, stream>>>(gates, c, h, hsum, hp, rem, Whalt, bhalt);
        }

        // xm = rem * hsum / T   (into h buffer)
        float* xm = h;
        avg_k<<<ew_grid, blk, 0, stream>>>(hsum, rem, xm);

        float* hmid = gates;  // [Bc, 4*768]
        float* eo   = xwi;    // [Bc, 4*768]
        for (int l = 0; l < 2; l++) {
            const float* gWl = gateW + (size_t)l * En * Hn;
            const float* gbl = gateb + (size_t)l * En;
            const float* W1l = W1 + (size_t)l * En * Hn * Hn;
            const float* b1l = b1 + (size_t)l * En * Hn;
            const float* W2l = W2 + (size_t)l * En * Dn * Hn;
            const float* b2l = b2 + (size_t)l * En * Dn;

            moe_gate_k<<<Bc, blk, 0, stream>>>(xm, gWl, gbl, wbuf, ibuf);

            // hmid = relu(xm @ W1l^T + b1l)   (all 4 experts: N = 3072)
            gemm128<false, true, true><<<gBig, blk, 0, stream>>>(
                xm, Hn, W1l, Hn, hmid, G4, nullptr, 0, b1l, Bc, G4, Hn, 0, 0, 0, 0);

            // eo[:, e*768:(e+1)*768] = hmid[:, e*768:...] @ W2l[e]^T + b2l[e]
            gemm128<false, true, false><<<gGrp, blk, 0, stream>>>(
                hmid, G4, W2l, Hn, eo, G4, nullptr, 0, b2l, Bc, Hn, Hn,
                (long)Hn, (long)Hn * Hn, (long)Hn, (long)Hn);

            float* dst = (l == 0) ? xm : c;   // level-1 result -> pre-LN buffer
            combine_k<<<ew_grid, blk, 0, stream>>>(eo, wbuf, ibuf, dst);
        }

        layernorm_k<<<Bc, blk, 0, stream>>>(c, gamma, beta, outc);
    }
}

// Round 3
// 7327.057 us; speedup vs baseline: 1.8827x; 1.8827x over previous
//
#include <hip/hip_runtime.h>
#include <cstdint>
#include <cstddef>

// Problem constants
#define Bn 16384
#define Dn 768
#define Hn 768
#define G4 3072
#define Tn 10
#define LO_SCALE 4096.0f
#define LO_INV   (1.0f/4096.0f)

typedef _Float16 f16;
typedef _Float16 f16x8 __attribute__((ext_vector_type(8)));
typedef float    f32x4 __attribute__((ext_vector_type(4)));

__device__ __forceinline__ float sigm(float x) { return 1.f / (1.f + expf(-x)); }

__device__ __forceinline__ void gll16(const void* g, void* l) {
    __builtin_amdgcn_global_load_lds((const __attribute__((address_space(1))) void*)g,
                                     (__attribute__((address_space(3))) void*)l, 16, 0, 0);
}

// ---------------------------------------------------------------------------
// Split-fp16 MFMA GEMM: C[M,N] = A[M,K=768] @ Bt[N,K=768]^T
// A = Ah + Al/4096, Bt = Bh + Bl/4096 (fp16 pairs). 3 MFMA products (hh, h*l, l*h),
// dual fp32 accumulators, combine acc + accx/4096 => ~fp32 accuracy.
// 128x128 tile, BK=32, 256 thr (4 waves, 64x64/wave), mfma_f32_16x16x32_f16.
// global_load_lds width-16 staging; XOR-swizzled LDS (2-way conflicts only).
// EPI: 0=f32 out(+bias,relu), 1=split f16 out, 2=f16 out, 3=fused LSTM gates.
// EPI3 expects gate-interleaved permuted columns: P = (j>>4)*64 + g*16 + (j&15).
// ---------------------------------------------------------------------------
template <bool SPLIT, int EPI, bool BIAS, bool RELU>
__global__ __launch_bounds__(256) void mgemm(
    const f16* __restrict__ Ah, const f16* __restrict__ Al, int lda,
    const f16* __restrict__ Bh, const f16* __restrict__ Bl,
    float* __restrict__ Cf, f16* __restrict__ Ch, f16* __restrict__ Cl, int ldc,
    const float* __restrict__ bias,
    const float* __restrict__ xwi, float* __restrict__ cst, float* __restrict__ hsum,
    f16* __restrict__ hh_out, f16* __restrict__ hl_out,
    long aZ, long bZ, long cZ, long biasZ)
{
    const int z = blockIdx.z;
    if (z) {
        Ah += (long)z * aZ; if (SPLIT) Al += (long)z * aZ;
        Bh += (long)z * bZ; if (SPLIT) Bl += (long)z * bZ;
        if (EPI == 0) Cf += (long)z * cZ;
        if (EPI == 1 || EPI == 2) { Ch += (long)z * cZ; if (EPI == 1) Cl += (long)z * cZ; }
        if (BIAS) bias += (long)z * biasZ;
    }
    __shared__ __align__(16) f16 sA[2][4096];   // [hi/lo][128 rows x 32 k]
    __shared__ __align__(16) f16 sB[2][4096];

    const int tid  = threadIdx.x;
    const int w    = tid >> 6, lane = tid & 63;
    const int quad = lane >> 4, l15 = lane & 15;
    const int m0 = blockIdx.x * 128, n0 = blockIdx.y * 128;
    const int wm = (w >> 1) * 64,   wn = (w & 1) * 64;

    f32x4 acc[4][4], accx[4][4];
#pragma unroll
    for (int i = 0; i < 4; i++)
#pragma unroll
        for (int j = 0; j < 4; j++) {
            acc[i][j]  = (f32x4){0.f, 0.f, 0.f, 0.f};
            accx[i][j] = (f32x4){0.f, 0.f, 0.f, 0.f};
        }

    for (int k0 = 0; k0 < 768; k0 += 32) {
        __syncthreads();
#pragma unroll
        for (int u = 0; u < 2; u++) {
            int s = u * 256 + tid;          // 512 slots of 8 halves per tile
            int r = s >> 2;
            int c = ((s & 3) - (r >> 1)) & 3;   // inverse swizzle
            gll16(Ah + (long)(m0 + r) * lda + k0 + c * 8, &sA[0][s * 8]);
            gll16(Bh + (long)(n0 + r) * 768 + k0 + c * 8, &sB[0][s * 8]);
            if (SPLIT) {
                gll16(Al + (long)(m0 + r) * lda + k0 + c * 8, &sA[1][s * 8]);
                gll16(Bl + (long)(n0 + r) * 768 + k0 + c * 8, &sB[1][s * 8]);
            }
        }
        __syncthreads();

        f16x8 ah[4], al[4], bh[4], bl[4];
#pragma unroll
        for (int t = 0; t < 4; t++) {
            int ra = wm + t * 16 + l15;
            int ca = (quad + (ra >> 1)) & 3;
            ah[t] = *(const f16x8*)&sA[0][ra * 32 + ca * 8];
            if (SPLIT) al[t] = *(const f16x8*)&sA[1][ra * 32 + ca * 8];
            int rb = wn + t * 16 + l15;
            int cb = (quad + (rb >> 1)) & 3;
            bh[t] = *(const f16x8*)&sB[0][rb * 32 + cb * 8];
            if (SPLIT) bl[t] = *(const f16x8*)&sB[1][rb * 32 + cb * 8];
        }
#pragma unroll
        for (int i = 0; i < 4; i++)
#pragma unroll
            for (int j = 0; j < 4; j++) {
                acc[i][j] = __builtin_amdgcn_mfma_f32_16x16x32_f16(ah[i], bh[j], acc[i][j], 0, 0, 0);
                if (SPLIT) {
                    accx[i][j] = __builtin_amdgcn_mfma_f32_16x16x32_f16(ah[i], bl[j], accx[i][j], 0, 0, 0);
                    accx[i][j] = __builtin_amdgcn_mfma_f32_16x16x32_f16(al[i], bh[j], accx[i][j], 0, 0, 0);
                }
            }
    }

    if (EPI == 3) {
        // Fused LSTM pointwise. Lane owns h-index j = ((n0+wn)>>2) + l15; nt = gate.
        const int j = ((n0 + wn) >> 2) + l15;
#pragma unroll
        for (int i = 0; i < 4; i++) {
#pragma unroll
            for (int reg = 0; reg < 4; reg++) {
                int r = m0 + wm + i * 16 + quad * 4 + reg;
                long xb = (long)r * G4 + n0 + wn + l15;
                float iv = acc[i][0][reg] + accx[i][0][reg] * LO_INV + xwi[xb];
                float fv = acc[i][1][reg] + accx[i][1][reg] * LO_INV + xwi[xb + 16];
                float gv = acc[i][2][reg] + accx[i][2][reg] * LO_INV + xwi[xb + 32];
                float ov = acc[i][3][reg] + accx[i][3][reg] * LO_INV + xwi[xb + 48];
                long ci = (long)r * Hn + j;
                float cv = sigm(fv) * cst[ci] + sigm(iv) * tanhf(gv);
                float hv = sigm(ov) * tanhf(cv);
                cst[ci] = cv;
                hsum[ci] += hv;
                f16 hh = (f16)hv;
                hh_out[ci] = hh;
                hl_out[ci] = (f16)((hv - (float)hh) * LO_SCALE);
            }
        }
    } else {
#pragma unroll
        for (int i = 0; i < 4; i++)
#pragma unroll
            for (int j = 0; j < 4; j++) {
                int col = n0 + wn + j * 16 + l15;
                float bv = BIAS ? bias[col] : 0.f;
#pragma unroll
                for (int reg = 0; reg < 4; reg++) {
                    int r = m0 + wm + i * 16 + quad * 4 + reg;
                    float v = acc[i][j][reg] + (SPLIT ? accx[i][j][reg] * LO_INV : 0.f) + bv;
                    if (RELU) v = v > 0.f ? v : 0.f;
                    long o = (long)r * ldc + col;
                    if (EPI == 0) Cf[o] = v;
                    else if (EPI == 2) Ch[o] = (f16)v;
                    else {
                        f16 hh = (f16)v;
                        Ch[o] = hh;
                        Cl[o] = (f16)((v - (float)hh) * LO_SCALE);
                    }
                }
            }
    }
}

// ----------------------------- support kernels -----------------------------

__global__ void split_plain_k(const float* __restrict__ src, f16* __restrict__ dh,
                              f16* __restrict__ dl, long n) {
    long i = (long)blockIdx.x * 256 + threadIdx.x;
    if (i < n) {
        float v = src[i];
        f16 h = (f16)v;
        dh[i] = h;
        dl[i] = (f16)((v - (float)h) * LO_SCALE);
    }
}

// permuted split for Wi/Wh [3072 x 768]: dst row P <- src row g*768 + j,
// where j = (P>>6)*16 + (P&15), g = (P>>4)&3.
__global__ void split_perm_k(const float* __restrict__ src, f16* __restrict__ dh,
                             f16* __restrict__ dl) {
    int P = blockIdx.x;
    int q = ((P >> 4) & 3) * Hn + (P >> 6) * 16 + (P & 15);
    const float* s = src + (long)q * 768;
    long o = (long)P * 768;
#pragma unroll
    for (int u = 0; u < 3; u++) {
        int kk = threadIdx.x + u * 256;
        float v = s[kk];
        f16 h = (f16)v;
        dh[o + kk] = h;
        dl[o + kk] = (f16)((v - (float)h) * LO_SCALE);
    }
}

__global__ void bsum_perm_k(const float* __restrict__ bi, const float* __restrict__ bh,
                            float* __restrict__ bsum) {
    int P = blockIdx.x * 256 + threadIdx.x;
    if (P < G4) {
        int q = ((P >> 4) & 3) * Hn + (P >> 6) * 16 + (P & 15);
        bsum[P] = bi[q] + bh[q];
    }
}

// t=0 LSTM step from zero state; xwi is permuted-column layout.
__global__ __launch_bounds__(256) void lstm0_k(
    const float* __restrict__ xwi, float* __restrict__ cst, float* __restrict__ hsum,
    f16* __restrict__ hh, f16* __restrict__ hl,
    float* __restrict__ hp, float* __restrict__ rem,
    const float* __restrict__ Whalt, const float* __restrict__ bhalt)
{
    const int row = blockIdx.x, tid = threadIdx.x;
    const float* xr = xwi + (long)row * G4;
    const long hb = (long)row * Hn;
    float part = 0.f;
#pragma unroll
    for (int u = 0; u < 3; u++) {
        int j = tid + u * 256;
        int Pb = (j >> 4) * 64 + (j & 15);
        float iv = xr[Pb], fv = xr[Pb + 16], gv = xr[Pb + 32], ov = xr[Pb + 48];
        (void)fv;
        float cv = sigm(iv) * tanhf(gv);
        float hv = sigm(ov) * tanhf(cv);
        cst[hb + j] = cv;
        hsum[hb + j] = hv;
        f16 h = (f16)hv;
        hh[hb + j] = h;
        hl[hb + j] = (f16)((hv - (float)h) * LO_SCALE);
        part += hv * Whalt[j];
    }
    __shared__ float red[256];
    red[tid] = part;
    __syncthreads();
    for (int s = 128; s > 0; s >>= 1) {
        if (tid < s) red[tid] += red[tid + s];
        __syncthreads();
    }
    if (tid == 0) {
        float y = sigm(red[0] + bhalt[0]);
        hp[row] = y;
        rem[row] = 1.f - y;
    }
}

// halting head for steps t>=1 (h from split pair)
__global__ __launch_bounds__(256) void halt_k(
    const f16* __restrict__ hh, const f16* __restrict__ hl,
    float* __restrict__ hp, float* __restrict__ rem,
    const float* __restrict__ Whalt, const float* __restrict__ bhalt)
{
    const int row = blockIdx.x, tid = threadIdx.x;
    const long hb = (long)row * Hn;
    float part = 0.f;
#pragma unroll
    for (int u = 0; u < 3; u++) {
        int j = tid + u * 256;
        float hv = (float)hh[hb + j] + (float)hl[hb + j] * LO_INV;
        part += hv * Whalt[j];
    }
    __shared__ float red[256];
    red[tid] = part;
    __syncthreads();
    for (int s = 128; s > 0; s >>= 1) {
        if (tid < s) red[tid] += red[tid + s];
        __syncthreads();
    }
    if (tid == 0) {
        float y = sigm(red[0] + bhalt[0]);
        float p = hp[row];
        float np = p + y * (1.f - p);
        hp[row] = np;
        rem[row] += 1.f - np;
    }
}

// xm = rem*hsum/T, plus split
__global__ void avgsplit_k(const float* __restrict__ hsum, const float* __restrict__ rem,
                           float* __restrict__ xm, f16* __restrict__ xmh, f16* __restrict__ xml) {
    long i = (long)blockIdx.x * 256 + threadIdx.x;
    int row = (int)(i / Hn);
    float v = rem[row] * hsum[i] * (1.f / (float)Tn);
    xm[i] = v;
    f16 h = (f16)v;
    xmh[i] = h;
    xml[i] = (f16)((v - (float)h) * LO_SCALE);
}

__global__ __launch_bounds__(256) void moe_gate_k(
    const float* __restrict__ xm, const float* __restrict__ gW,
    const float* __restrict__ gb, float* __restrict__ wout, int* __restrict__ idxout)
{
    const int row = blockIdx.x, tid = threadIdx.x;
    const float* xr = xm + (long)row * Hn;
    float p[4] = {0.f, 0.f, 0.f, 0.f};
#pragma unroll
    for (int u = 0; u < 3; u++) {
        int j = tid + u * 256;
        float xv = xr[j];
        p[0] += xv * gW[j];
        p[1] += xv * gW[Hn + j];
        p[2] += xv * gW[2 * Hn + j];
        p[3] += xv * gW[3 * Hn + j];
    }
    __shared__ float red[256];
    __shared__ float logit[4];
    for (int e = 0; e < 4; e++) {
        red[tid] = p[e];
        __syncthreads();
        for (int s = 128; s > 0; s >>= 1) {
            if (tid < s) red[tid] += red[tid + s];
            __syncthreads();
        }
        if (tid == 0) logit[e] = red[0] + gb[e];
        __syncthreads();
    }
    if (tid == 0) {
        int i0 = 0;
        for (int e = 1; e < 4; e++) if (logit[e] > logit[i0]) i0 = e;
        int i1 = -1;
        for (int e = 0; e < 4; e++) {
            if (e == i0) continue;
            if (i1 < 0 || logit[e] > logit[i1]) i1 = e;
        }
        float ex = expf(logit[i1] - logit[i0]);
        wout[2 * row] = 1.f / (1.f + ex);
        wout[2 * row + 1] = ex / (1.f + ex);
        idxout[2 * row] = i0;
        idxout[2 * row + 1] = i1;
    }
}

template <bool SO>
__global__ void combine_k(const float* __restrict__ eo, const float* __restrict__ wv,
                          const int* __restrict__ idx, float* __restrict__ dst,
                          f16* __restrict__ dh, f16* __restrict__ dl) {
    long i = (long)blockIdx.x * 256 + threadIdx.x;
    int row = (int)(i / Hn);
    int d = (int)(i - (long)row * Hn);
    long base = (long)row * G4;
    float v = wv[2 * row]     * eo[base + (long)idx[2 * row]     * Hn + d]
            + wv[2 * row + 1] * eo[base + (long)idx[2 * row + 1] * Hn + d];
    dst[i] = v;
    if (SO) {
        f16 h = (f16)v;
        dh[i] = h;
        dl[i] = (f16)((v - (float)h) * LO_SCALE);
    }
}

__global__ __launch_bounds__(256) void layernorm_k(
    const float* __restrict__ in, const float* __restrict__ gamma,
    const float* __restrict__ beta, float* __restrict__ out)
{
    const int row = blockIdx.x, tid = threadIdx.x;
    const float* xr = in + (long)row * Dn;
    float v[3], s = 0.f, s2 = 0.f;
#pragma unroll
    for (int u = 0; u < 3; u++) {
        v[u] = xr[tid + u * 256];
        s += v[u];
        s2 += v[u] * v[u];
    }
    __shared__ float r1[256], r2[256];
    __shared__ float smu, srs;
    r1[tid] = s; r2[tid] = s2;
    __syncthreads();
    for (int st = 128; st > 0; st >>= 1) {
        if (tid < st) { r1[tid] += r1[tid + st]; r2[tid] += r2[tid + st]; }
        __syncthreads();
    }
    if (tid == 0) {
        float mu = r1[0] * (1.f / (float)Dn);
        float var = r2[0] * (1.f / (float)Dn) - mu * mu;
        smu = mu;
        srs = 1.f / sqrtf(var + 1e-5f);
    }
    __syncthreads();
    float mu = smu, rs = srs;
#pragma unroll
    for (int u = 0; u < 3; u++) {
        int j = tid + u * 256;
        out[(long)row * Dn + j] = (v[u] - mu) * rs * gamma[j] + beta[j];
    }
}

// ---------------------------------------------------------------------------

extern "C" void kernel_launch(void* const* d_in, const int* in_sizes, int n_in,
                              void* d_out, int out_size, void* d_ws, size_t ws_size,
                              hipStream_t stream) {
    (void)in_sizes; (void)n_in; (void)out_size;
    const float* x     = (const float*)d_in[0];
    const float* Wi    = (const float*)d_in[1];
    const float* Wh    = (const float*)d_in[2];
    const float* bi    = (const float*)d_in[3];
    const float* bh    = (const float*)d_in[4];
    const float* Whalt = (const float*)d_in[5];
    const float* bhalt = (const float*)d_in[6];
    const float* gateW = (const float*)d_in[7];
    const float* gateb = (const float*)d_in[8];
    const float* W1    = (const float*)d_in[9];
    const float* b1    = (const float*)d_in[10];
    const float* W2    = (const float*)d_in[11];
    const float* b2    = (const float*)d_in[12];
    const float* gamma = (const float*)d_in[13];
    const float* beta  = (const float*)d_in[14];
    float* out = (float*)d_out;

    // ---- workspace carving -------------------------------------------------
    char* p = (char*)d_ws;
    auto carve = [&](size_t bytes) { char* r = p; p += (bytes + 255) & ~(size_t)255; return r; };

    const long WIHN = (long)G4 * 768;        // 2,359,296
    const long WEHN = (long)8 * 768 * 768;   // 4,718,592 (both levels)
    f16* Wih = (f16*)carve(WIHN * 2); f16* Wil = (f16*)carve(WIHN * 2);
    f16* Whh = (f16*)carve(WIHN * 2); f16* Whl = (f16*)carve(WIHN * 2);
    f16* W1h = (f16*)carve(WEHN * 2); f16* W1l = (f16*)carve(WEHN * 2);
    f16* W2h = (f16*)carve(WEHN * 2); f16* W2l = (f16*)carve(WEHN * 2);
    float* bsum = (float*)carve(G4 * 4);
    size_t fixed = (size_t)(p - (char*)d_ws);

    // per-row bytes: xh/xl 3072 + xwi 12288 + c 3072 + hsum 3072 + xm 3072
    //              + xmh/xml 3072 + h(4) 6144 + hmid 12288 + small 24 = 46056 (+pads)
    int Bc = Bn;
    while (Bc > 128) {
        size_t need = fixed + (size_t)Bc * 46104 + 32 * 256;
        if (need <= ws_size) break;
        Bc >>= 1;
    }
    const int nChunks = Bn / Bc;

    f16*   xh    = (f16*)carve((size_t)Bc * 768 * 2);
    f16*   xl    = (f16*)carve((size_t)Bc * 768 * 2);
    float* xwi   = (float*)carve((size_t)Bc * G4 * 4);   // reused as eo in MoE
    float* cst   = (float*)carve((size_t)Bc * 768 * 4);
    float* hsumb = (float*)carve((size_t)Bc * 768 * 4);  // reused as pre-LN dst
    float* xm    = (float*)carve((size_t)Bc * 768 * 4);
    f16*   xmh   = (f16*)carve((size_t)Bc * 768 * 2);
    f16*   xml   = (f16*)carve((size_t)Bc * 768 * 2);
    f16*   h0h   = (f16*)carve((size_t)Bc * 768 * 2);
    f16*   h0l   = (f16*)carve((size_t)Bc * 768 * 2);
    f16*   h1h   = (f16*)carve((size_t)Bc * 768 * 2);
    f16*   h1l   = (f16*)carve((size_t)Bc * 768 * 2);
    f16*   hmh   = (f16*)carve((size_t)Bc * G4 * 2);
    f16*   hml   = (f16*)carve((size_t)Bc * G4 * 2);
    float* hp    = (float*)carve((size_t)Bc * 4);
    float* rem   = (float*)carve((size_t)Bc * 4);
    float* wbuf  = (float*)carve((size_t)Bc * 2 * 4);
    int*   ibuf  = (int*)carve((size_t)Bc * 2 * 4);

    // ---- weight prep (once per call) --------------------------------------
    split_perm_k<<<G4, 256, 0, stream>>>(Wi, Wih, Wil);
    split_perm_k<<<G4, 256, 0, stream>>>(Wh, Whh, Whl);
    split_plain_k<<<(int)((WEHN + 255) / 256), 256, 0, stream>>>(W1, W1h, W1l, WEHN);
    split_plain_k<<<(int)((WEHN + 255) / 256), 256, 0, stream>>>(W2, W2h, W2l, WEHN);
    bsum_perm_k<<<G4 / 256, 256, 0, stream>>>(bi, bh, bsum);

    dim3 blk(256);
    dim3 g24(Bc / 128, 24, 1);
    dim3 g6z(Bc / 128, 6, 4);
    const int ew = Bc * 3;   // (Bc*768)/256

    const long EXP_OFF = (long)4 * 768 * 768;  // per-level offset in W1/W2 (elems)

    for (int ch = 0; ch < nChunks; ch++) {
        const float* xc = x + (size_t)ch * Bc * Dn;
        float* outc = out + (size_t)ch * Bc * Dn;

        split_plain_k<<<ew, blk, 0, stream>>>(xc, xh, xl, (long)Bc * 768);

        // xwi = x @ Wi^T + (bi+bh)   (permuted columns)
        mgemm<true, 0, true, false><<<g24, blk, 0, stream>>>(
            xh, xl, 768, Wih, Wil, xwi, nullptr, nullptr, G4, bsum,
            nullptr, nullptr, nullptr, nullptr, nullptr, 0, 0, 0, 0);

        lstm0_k<<<Bc, blk, 0, stream>>>(xwi, cst, hsumb, h0h, h0l, hp, rem, Whalt, bhalt);

        for (int t = 1; t < Tn; t++) {
            f16* rah = (t & 1) ? h0h : h1h;   // read buf (t-1)&1
            f16* ral = (t & 1) ? h0l : h1l;
            f16* wah = (t & 1) ? h1h : h0h;   // write buf t&1
            f16* wal = (t & 1) ? h1l : h0l;
            mgemm<true, 3, false, false><<<g24, blk, 0, stream>>>(
                rah, ral, 768, Whh, Whl, nullptr, nullptr, nullptr, 0, nullptr,
                xwi, cst, hsumb, wah, wal, 0, 0, 0, 0);
            halt_k<<<Bc, blk, 0, stream>>>(wah, wal, hp, rem, Whalt, bhalt);
        }

        avgsplit_k<<<ew, blk, 0, stream>>>(hsumb, rem, xm, xmh, xml);

        float* eo = xwi;  // reuse
        for (int l = 0; l < 2; l++) {
            moe_gate_k<<<Bc, blk, 0, stream>>>(xm, gateW + (long)l * G4, gateb + l * 4, wbuf, ibuf);
            if (l == 0) {
                mgemm<true, 1, true, true><<<g24, blk, 0, stream>>>(
                    xmh, xml, 768, W1h, W1l, nullptr, hmh, hml, G4, b1,
                    nullptr, nullptr, nullptr, nullptr, nullptr, 0, 0, 0, 0);
                mgemm<true, 0, true, false><<<g6z, blk, 0, stream>>>(
                    hmh, hml, G4, W2h, W2l, eo, nullptr, nullptr, G4, b2,
                    nullptr, nullptr, nullptr, nullptr, nullptr,
                    768, (long)768 * 768, 768, 768);
                combine_k<true><<<ew, blk, 0, stream>>>(eo, wbuf, ibuf, xm, xmh, xml);
            } else {
                mgemm<false, 2, true, true><<<g24, blk, 0, stream>>>(
                    xmh, nullptr, 768, W1h + EXP_OFF, nullptr, nullptr, hmh, nullptr, G4,
                    b1 + G4, nullptr, nullptr, nullptr, nullptr, nullptr, 0, 0, 0, 0);
                mgemm<false, 0, true, false><<<g6z, blk, 0, stream>>>(
                    hmh, nullptr, G4, W2h + EXP_OFF, nullptr, eo, nullptr, nullptr, G4,
                    b2 + G4, nullptr, nullptr, nullptr, nullptr, nullptr,
                    768, (long)768 * 768, 768, 768);
                combine_k<false><<<ew, blk, 0, stream>>>(eo, wbuf, ibuf, hsumb, nullptr, nullptr);
            }
        }

        layernorm_k<<<Bc, blk, 0, stream>>>(hsumb, gamma, beta, outc);
    }
}